// Round 17
// baseline (57.624 us; speedup 1.0000x reference)
//
#include <hip/hip_runtime.h>

#define N_NODES 80000
#define N_EDGES 1280000
#define D 64            // D_IN == D_OUT == 64
#define NB 1250         // bins of 64 nodes: 1250*64 = 80000
#define NPB 64          // nodes per bin
#define CAPB 1536       // per-bin record capacity (Poisson(1024) + ~16 sigma)
#define PT 1024         // partition block threads
#define CHUNK 16        // edges per partition thread (contiguous, int4-vectorized)
#define EPB (PT * CHUNK)                  // 16384 edges per partition block
#define NBLK ((N_EDGES + EPB - 1) / EPB)  // 79 partition blocks
#define GEMM_BLOCKS ((N_NODES + 255) / 256)   // 313 gemm blocks (256 rows, 16 waves)

// ---------------- workspace layout (bytes) ----------------
#define OFF_SUP   0u
#define SUP_BYTES (N_NODES * D * 2u)                 // 10,240,000 (bf16 support)
#define OFF_CNT   (OFF_SUP + SUP_BYTES)
#define OFF_OVC   (OFF_CNT + 5120u)
#define OFF_REC   (OFF_OVC + 256u)
#define REC_BYTES (NB * CAPB * 8u)                   // 15,360,000
#define OFF_OVF   (OFF_REC + REC_BYTES)
#define ZERO_INTS 1344                               // cnt region + ovf_cnt

typedef __attribute__((ext_vector_type(8))) __bf16 bf16x8;
typedef __attribute__((ext_vector_type(4))) float  floatx4;

// scalar f32 -> bf16 RNE
__device__ inline unsigned short bf16_rne(float f) {
    unsigned u = __float_as_uint(f);
    u += 0x7fffu + ((u >> 16) & 1u);
    return (unsigned short)(u >> 16);
}

__device__ inline bf16x8 pack8(float4 a, float4 b) {
    union { unsigned short s[8]; bf16x8 v; } U;
    U.s[0] = bf16_rne(a.x); U.s[1] = bf16_rne(a.y);
    U.s[2] = bf16_rne(a.z); U.s[3] = bf16_rne(a.w);
    U.s[4] = bf16_rne(b.x); U.s[5] = bf16_rne(b.y);
    U.s[6] = bf16_rne(b.z); U.s[7] = bf16_rne(b.w);
    return U.v;
}

// ---------------------------------------------------------------------------
// Kernel 0: zero bin counters + overflow counter (tiny, 1 block)
// ---------------------------------------------------------------------------
__global__ __launch_bounds__(1024) void zero_cnt(int* __restrict__ z) {
    for (int i = threadIdx.x; i < ZERO_INTS; i += 1024) z[i] = 0;
}

// ---------------------------------------------------------------------------
// Kernel 1 (fused): blockIdx < GEMM_BLOCKS -> support = X @ W via MFMA
// (bf16 in/out, f32 accum), else -> single-pass edge partition with
// int4-vectorized edge loads (16 contiguous edges per thread -> ~13-record
// per-bin runs, lower record-write line amplification).
// record = (src | dst_lo<<17, weight)
// ---------------------------------------------------------------------------
__global__ __launch_bounds__(1024) void gemm_partition(const float* __restrict__ x,
                                                       const float* __restrict__ w,
                                                       unsigned* __restrict__ sup,
                                                       const int* __restrict__ ei,
                                                       const float* __restrict__ ew,
                                                       int* __restrict__ cnt,
                                                       int2* __restrict__ recs,
                                                       int* __restrict__ ovf_cnt,
                                                       int* __restrict__ ovf_list) {
    // union: gemm -> wt (8 KB) + out-staging (32 KB); partition -> hist (5 KB)
    __shared__ __align__(16) char smem[40960];
    const int tid = threadIdx.x;

    if (blockIdx.x < GEMM_BLOCKS) {
        // ---- MFMA GEMM: 16 waves/block, one 16-row x 64-col tile per wave --
        const int wave = tid >> 6;
        const int lane = tid & 63;
        const int r0 = blockIdx.x * 256 + wave * 16;

        // stage W transposed -> bf16 with XOR swizzle (conflict-free B reads)
        for (int idx = tid; idx < 4096; idx += 1024) {
            const int k = idx >> 6, n = idx & 63;
            const unsigned byte = (unsigned)((n * 64 + k) * 2) ^ (unsigned)((n & 7) << 4);
            *(unsigned short*)(smem + byte) = bf16_rne(w[idx]);
        }
        __syncthreads();

        if (r0 < N_NODES) {     // 80000 % 16 == 0 -> tile fully valid
            const int mrow = lane & 15;      // A row / B col / D col lane bits
            const int q    = lane >> 4;      // k-quadrant
            const float* xr = x + (size_t)(r0 + mrow) * D;

            // A frags: k = q*8 + i (+32 for frag1)
            const bf16x8 A0 = pack8(*(const float4*)(xr + q * 8),
                                    *(const float4*)(xr + q * 8 + 4));
            const bf16x8 A1 = pack8(*(const float4*)(xr + 32 + q * 8),
                                    *(const float4*)(xr + 32 + q * 8 + 4));

            floatx4 acc[4];
#pragma unroll
            for (int t = 0; t < 4; ++t) acc[t] = (floatx4){0.f, 0.f, 0.f, 0.f};

#pragma unroll
            for (int t = 0; t < 4; ++t) {
                const int n = t * 16 + mrow;
                const unsigned b0 = (unsigned)((n * 64 + q * 8) * 2) ^ (unsigned)((n & 7) << 4);
                const unsigned b1 = (unsigned)((n * 64 + 32 + q * 8) * 2) ^ (unsigned)((n & 7) << 4);
                const bf16x8 B0 = *(const bf16x8*)(smem + b0);
                const bf16x8 B1 = *(const bf16x8*)(smem + b1);
                acc[t] = __builtin_amdgcn_mfma_f32_16x16x32_bf16(A0, B0, acc[t], 0, 0, 0);
                acc[t] = __builtin_amdgcn_mfma_f32_16x16x32_bf16(A1, B1, acc[t], 0, 0, 0);
            }

            // D: col = lane&15, row = (lane>>4)*4 + reg  (m89-verified)
            unsigned short* so = (unsigned short*)(smem + 8192) + wave * 1024;
#pragma unroll
            for (int t = 0; t < 4; ++t) {
#pragma unroll
                for (int r = 0; r < 4; ++r) {
                    so[(q * 4 + r) * 64 + t * 16 + mrow] = bf16_rne(acc[t][r]);
                }
            }

            // wave-local staging readback (same wave wrote this 2 KB region)
            __builtin_amdgcn_wave_barrier();
            const uint4* lo = (const uint4*)(smem + 8192 + wave * 2048);
            const uint4 v0 = lo[lane];
            const uint4 v1 = lo[64 + lane];
            char* supb = (char*)sup;
            ((uint4*)(supb + (size_t)(r0 + (lane >> 3)) * 128))[lane & 7] = v0;
            ((uint4*)(supb + (size_t)(r0 + 8 + (lane >> 3)) * 128))[lane & 7] = v1;
        }
    } else {
        // ---- Partition branch: 16 contiguous edges/thread (4x int4 per
        // stream) -> LDS histogram -> 1 global atomic per non-empty bin ->
        // LDS-cursor placement into contiguous streams ----
        int* hist = (int*)smem;
        const int e0 = (blockIdx.x - GEMM_BLOCKS) * EPB;

        for (int i = tid; i < NB; i += PT) hist[i] = 0;
        __syncthreads();

        const int base = e0 + tid * CHUNK;
        const bool active = base < N_EDGES;   // full 16-chunk valid (N_EDGES%16==0)
        int r_meta[CHUNK], r_w[CHUNK], r_bin[CHUNK];
        if (active) {
            int ss[CHUNK], dd[CHUNK];
            float ww[CHUNK];
#pragma unroll
            for (int v = 0; v < CHUNK / 4; ++v) {
                const int4 s = *(const int4*)(ei + base + v * 4);
                const int4 d = *(const int4*)(ei + N_EDGES + base + v * 4);
                const float4 f = *(const float4*)(ew + base + v * 4);
                ss[v*4+0]=s.x; ss[v*4+1]=s.y; ss[v*4+2]=s.z; ss[v*4+3]=s.w;
                dd[v*4+0]=d.x; dd[v*4+1]=d.y; dd[v*4+2]=d.z; dd[v*4+3]=d.w;
                ww[v*4+0]=f.x; ww[v*4+1]=f.y; ww[v*4+2]=f.z; ww[v*4+3]=f.w;
            }
#pragma unroll
            for (int i = 0; i < CHUNK; ++i) {
                r_meta[i] = ss[i] | ((dd[i] & 63) << 17);
                r_w[i]    = __float_as_int(ww[i]);
                r_bin[i]  = dd[i] >> 6;
                atomicAdd(&hist[r_bin[i]], 1);
            }
        }
        __syncthreads();

        for (int b = tid; b < NB; b += PT) {
            const int c = hist[b];
            if (c > 0) hist[b] = atomicAdd(&cnt[b], c);
        }
        __syncthreads();

        if (active) {
#pragma unroll
            for (int i = 0; i < CHUNK; ++i) {
                const int slot = atomicAdd(&hist[r_bin[i]], 1);
                if (slot < CAPB) {
                    recs[(size_t)r_bin[i] * CAPB + slot] = make_int2(r_meta[i], r_w[i]);
                } else {
                    const int q2 = atomicAdd(ovf_cnt, 1);
                    ovf_list[q2] = base + i;
                }
            }
        }
    }
}

// ---------------------------------------------------------------------------
// Kernel 2: per-bin gather, 512 threads.  Records register-staged across
// count/scan barriers (<=3/thread), node-sorted into lcsr, then ONE 8-lane
// group per node with 16 B uint4 sup loads, unrolled x8 for load MLP.
// Overflow edges merged in-register.
// ---------------------------------------------------------------------------
__global__ __launch_bounds__(512) void gather_bins(const unsigned* __restrict__ sup,
                                                   const int* __restrict__ cnt,
                                                   const int2* __restrict__ recs,
                                                   const float* __restrict__ bias,
                                                   const int* __restrict__ ei,
                                                   const float* __restrict__ ew,
                                                   const int* __restrict__ ovf_cnt,
                                                   const int* __restrict__ ovf_list,
                                                   float* __restrict__ out) {
    __shared__ int2 lcsr[CAPB];              // 12,288 B (node-sorted)
    __shared__ int lcnt[NPB];
    __shared__ int lcur[NPB];
    __shared__ int loff[NPB + 1];

    const int tid = threadIdx.x;
    const int bin = blockIdx.x;

    if (tid < NPB) lcnt[tid] = 0;
    __syncthreads();

    int c = cnt[bin];
    c = c < CAPB ? c : CAPB;
    const int2* bk = recs + (size_t)bin * CAPB;
    const int novf = *ovf_cnt;               // hoisted; latency hides below

    // stage into registers (named, no scratch) + per-node counts
    const int i0 = tid, i1 = tid + 512, i2 = tid + 1024;
    int2 ra, rb, rc2;
    int na = -1, nb2 = -1, nc = -1;
    if (i0 < c) ra  = bk[i0];
    if (i1 < c) rb  = bk[i1];
    if (i2 < c) rc2 = bk[i2];
    if (i0 < c) { na  = (ra.x  >> 17) & 63; atomicAdd(&lcnt[na],  1); }
    if (i1 < c) { nb2 = (rb.x  >> 17) & 63; atomicAdd(&lcnt[nb2], 1); }
    if (i2 < c) { nc  = (rc2.x >> 17) & 63; atomicAdd(&lcnt[nc],  1); }
    __syncthreads();

    // wave 0: exclusive scan over 64 node counts
    if (tid < 64) {
        const int my = lcnt[tid];
        int v = my;
#pragma unroll
        for (int d = 1; d < 64; d <<= 1) {
            const int o = __shfl_up(v, d);
            if (tid >= d) v += o;
        }
        loff[tid + 1] = v;
        lcur[tid] = v - my;
        if (tid == 0) loff[0] = 0;
    }
    __syncthreads();

    // place register-held records into node-sorted order
    if (na  >= 0) { const int p = atomicAdd(&lcur[na],  1); lcsr[p] = ra;  }
    if (nb2 >= 0) { const int p = atomicAdd(&lcur[nb2], 1); lcsr[p] = rb;  }
    if (nc  >= 0) { const int p = atomicAdd(&lcur[nc],  1); lcsr[p] = rc2; }
    __syncthreads();

    // one 8-lane group per node; lane l owns channels [l*8, l*8+8)
    const int n = tid >> 3;       // node 0..63
    const int l = tid & 7;
    float4 accA = ((const float4*)bias)[l * 2];
    float4 accB = ((const float4*)bias)[l * 2 + 1];

    const int kend = loff[n + 1];
#pragma unroll 8
    for (int k = loff[n]; k < kend; ++k) {
        const int2 r = lcsr[k];                       // broadcast in group
        const float wc = __int_as_float(r.y);
        const uint4 sv = ((const uint4*)(sup + (size_t)(r.x & 0x1FFFF) * 32))[l];
        accA.x += wc * __uint_as_float(sv.x << 16);
        accA.y += wc * __uint_as_float(sv.x & 0xffff0000u);
        accA.z += wc * __uint_as_float(sv.y << 16);
        accA.w += wc * __uint_as_float(sv.y & 0xffff0000u);
        accB.x += wc * __uint_as_float(sv.z << 16);
        accB.y += wc * __uint_as_float(sv.z & 0xffff0000u);
        accB.z += wc * __uint_as_float(sv.w << 16);
        accB.w += wc * __uint_as_float(sv.w & 0xffff0000u);
    }

    // overflow merge (statistically zero entries; correctness safety net)
    for (int i = 0; i < novf; ++i) {
        const int e = ovf_list[i];
        const int dst = ei[N_EDGES + e];
        if ((dst >> 6) == bin && (dst & 63) == n) {
            const float wv = ew[e];
            const uint4 sv = ((const uint4*)(sup + (size_t)ei[e] * 32))[l];
            accA.x += wv * __uint_as_float(sv.x << 16);
            accA.y += wv * __uint_as_float(sv.x & 0xffff0000u);
            accA.z += wv * __uint_as_float(sv.y << 16);
            accA.w += wv * __uint_as_float(sv.y & 0xffff0000u);
            accB.x += wv * __uint_as_float(sv.z << 16);
            accB.y += wv * __uint_as_float(sv.z & 0xffff0000u);
            accB.z += wv * __uint_as_float(sv.w << 16);
            accB.w += wv * __uint_as_float(sv.w & 0xffff0000u);
        }
    }

    float4* orow = (float4*)(out + (size_t)(bin * NPB + n) * D);
    orow[l * 2]     = accA;
    orow[l * 2 + 1] = accB;
}

// ---------------------------------------------------------------------------
extern "C" void kernel_launch(void* const* d_in, const int* in_sizes, int n_in,
                              void* d_out, int out_size, void* d_ws, size_t ws_size,
                              hipStream_t stream) {
    const float* x      = (const float*)d_in[0];
    const int*   ei     = (const int*)d_in[1];
    const float* ew     = (const float*)d_in[2];
    const float* weight = (const float*)d_in[3];
    const float* bias   = (const float*)d_in[4];
    float* out = (float*)d_out;

    char* ws = (char*)d_ws;
    unsigned* sup   = (unsigned*)(ws + OFF_SUP);
    int*  cnt       = (int*)(ws + OFF_CNT);
    int*  ovf_cnt   = (int*)(ws + OFF_OVC);
    int2* recs      = (int2*)(ws + OFF_REC);
    int*  ovf_list  = (int*)(ws + OFF_OVF);

    // 0. zero bin/overflow counters (1 tiny block)
    zero_cnt<<<1, 1024, 0, stream>>>(cnt);

    // 1. fused: support = X @ W (MFMA)  ||  vectorized edge partition
    gemm_partition<<<GEMM_BLOCKS + NBLK, 1024, 0, stream>>>(
        x, weight, sup, ei, ew, cnt, recs, ovf_cnt, ovf_list);

    // 2. per-bin gather + bias + overflow merge + out write
    gather_bins<<<NB, 512, 0, stream>>>(sup, cnt, recs, bias,
                                        ei, ew, ovf_cnt, ovf_list, out);
}

// Round 18
// 51.057 us; speedup vs baseline: 1.1286x; 1.1286x over previous
//
#include <hip/hip_runtime.h>

#define N_NODES 80000
#define N_EDGES 1280000
#define D 64            // D_IN == D_OUT == 64
#define NB 1250         // bins of 64 nodes: 1250*64 = 80000
#define NPB 64          // nodes per bin
#define CAPB 1536       // per-bin record capacity (Poisson(1024) + ~16 sigma)
#define PT 1024         // partition block threads
#define CHUNK 8         // edges per partition thread (contiguous, int4-vectorized)
#define EPB (PT * CHUNK)                  // 8192 edges per partition block
#define NBLK ((N_EDGES + EPB - 1) / EPB)  // 157 partition blocks
#define GEMM_BLOCKS ((N_NODES + 255) / 256)   // 313 gemm blocks (256 rows, 16 waves)

// ---------------- workspace layout (bytes) ----------------
#define OFF_SUP   0u
#define SUP_BYTES (N_NODES * D * 2u)                 // 10,240,000 (bf16 support)
#define OFF_CNT   (OFF_SUP + SUP_BYTES)
#define OFF_OVC   (OFF_CNT + 5120u)
#define OFF_REC   (OFF_OVC + 256u)
#define REC_BYTES (NB * CAPB * 8u)                   // 15,360,000
#define OFF_OVF   (OFF_REC + REC_BYTES)
#define ZERO_INTS 1344                               // cnt region + ovf_cnt

typedef __attribute__((ext_vector_type(8))) __bf16 bf16x8;
typedef __attribute__((ext_vector_type(4))) float  floatx4;

// scalar f32 -> bf16 RNE
__device__ inline unsigned short bf16_rne(float f) {
    unsigned u = __float_as_uint(f);
    u += 0x7fffu + ((u >> 16) & 1u);
    return (unsigned short)(u >> 16);
}

__device__ inline bf16x8 pack8(float4 a, float4 b) {
    union { unsigned short s[8]; bf16x8 v; } U;
    U.s[0] = bf16_rne(a.x); U.s[1] = bf16_rne(a.y);
    U.s[2] = bf16_rne(a.z); U.s[3] = bf16_rne(a.w);
    U.s[4] = bf16_rne(b.x); U.s[5] = bf16_rne(b.y);
    U.s[6] = bf16_rne(b.z); U.s[7] = bf16_rne(b.w);
    return U.v;
}

// ---------------------------------------------------------------------------
// Kernel 0: zero bin counters + overflow counter (tiny, 1 block)
// ---------------------------------------------------------------------------
__global__ __launch_bounds__(1024) void zero_cnt(int* __restrict__ z) {
    for (int i = threadIdx.x; i < ZERO_INTS; i += 1024) z[i] = 0;
}

// ---------------------------------------------------------------------------
// Kernel 1 (fused): blockIdx < GEMM_BLOCKS -> support = X @ W via MFMA
// (bf16 in/out, f32 accum), else -> single-pass edge partition with
// int4-vectorized edge loads (8 contiguous edges per thread).
// record = (src | dst_lo<<17, weight)
// ---------------------------------------------------------------------------
__global__ __launch_bounds__(1024) void gemm_partition(const float* __restrict__ x,
                                                       const float* __restrict__ w,
                                                       unsigned* __restrict__ sup,
                                                       const int* __restrict__ ei,
                                                       const float* __restrict__ ew,
                                                       int* __restrict__ cnt,
                                                       int2* __restrict__ recs,
                                                       int* __restrict__ ovf_cnt,
                                                       int* __restrict__ ovf_list) {
    // union: gemm -> wt (8 KB) + out-staging (32 KB); partition -> hist (5 KB)
    __shared__ __align__(16) char smem[40960];
    const int tid = threadIdx.x;

    if (blockIdx.x < GEMM_BLOCKS) {
        // ---- MFMA GEMM: 16 waves/block, one 16-row x 64-col tile per wave --
        const int wave = tid >> 6;
        const int lane = tid & 63;
        const int r0 = blockIdx.x * 256 + wave * 16;

        // stage W transposed -> bf16 with XOR swizzle (conflict-free B reads)
        for (int idx = tid; idx < 4096; idx += 1024) {
            const int k = idx >> 6, n = idx & 63;
            const unsigned byte = (unsigned)((n * 64 + k) * 2) ^ (unsigned)((n & 7) << 4);
            *(unsigned short*)(smem + byte) = bf16_rne(w[idx]);
        }
        __syncthreads();

        if (r0 < N_NODES) {     // 80000 % 16 == 0 -> tile fully valid
            const int mrow = lane & 15;      // A row / B col / D col lane bits
            const int q    = lane >> 4;      // k-quadrant
            const float* xr = x + (size_t)(r0 + mrow) * D;

            // A frags: k = q*8 + i (+32 for frag1)
            const bf16x8 A0 = pack8(*(const float4*)(xr + q * 8),
                                    *(const float4*)(xr + q * 8 + 4));
            const bf16x8 A1 = pack8(*(const float4*)(xr + 32 + q * 8),
                                    *(const float4*)(xr + 32 + q * 8 + 4));

            floatx4 acc[4];
#pragma unroll
            for (int t = 0; t < 4; ++t) acc[t] = (floatx4){0.f, 0.f, 0.f, 0.f};

#pragma unroll
            for (int t = 0; t < 4; ++t) {
                const int n = t * 16 + mrow;
                const unsigned b0 = (unsigned)((n * 64 + q * 8) * 2) ^ (unsigned)((n & 7) << 4);
                const unsigned b1 = (unsigned)((n * 64 + 32 + q * 8) * 2) ^ (unsigned)((n & 7) << 4);
                const bf16x8 B0 = *(const bf16x8*)(smem + b0);
                const bf16x8 B1 = *(const bf16x8*)(smem + b1);
                acc[t] = __builtin_amdgcn_mfma_f32_16x16x32_bf16(A0, B0, acc[t], 0, 0, 0);
                acc[t] = __builtin_amdgcn_mfma_f32_16x16x32_bf16(A1, B1, acc[t], 0, 0, 0);
            }

            // D: col = lane&15, row = (lane>>4)*4 + reg  (m89-verified)
            unsigned short* so = (unsigned short*)(smem + 8192) + wave * 1024;
#pragma unroll
            for (int t = 0; t < 4; ++t) {
#pragma unroll
                for (int r = 0; r < 4; ++r) {
                    so[(q * 4 + r) * 64 + t * 16 + mrow] = bf16_rne(acc[t][r]);
                }
            }

            // wave-local staging readback: same wave wrote this 2 KB region;
            // CDNA waves are lockstep + per-wave LDS ops are in-order, so no
            // block barrier needed (saves one __syncthreads per block).
            __builtin_amdgcn_wave_barrier();
            const uint4* lo = (const uint4*)(smem + 8192 + wave * 2048);
            const uint4 v0 = lo[lane];
            const uint4 v1 = lo[64 + lane];
            char* supb = (char*)sup;
            ((uint4*)(supb + (size_t)(r0 + (lane >> 3)) * 128))[lane & 7] = v0;
            ((uint4*)(supb + (size_t)(r0 + 8 + (lane >> 3)) * 128))[lane & 7] = v1;
        }
    } else {
        // ---- Partition branch: int4-vectorized loads (8 contiguous edges
        // per thread) -> LDS histogram -> 1 global atomic per non-empty
        // bin -> LDS-cursor placement into contiguous streams ----
        int* hist = (int*)smem;
        const int e0 = (blockIdx.x - GEMM_BLOCKS) * EPB;

        for (int i = tid; i < NB; i += PT) hist[i] = 0;
        __syncthreads();

        const int base = e0 + tid * CHUNK;
        const bool active = base < N_EDGES;   // full 8-chunk valid
        int r_meta[CHUNK], r_w[CHUNK], r_bin[CHUNK];
        if (active) {
            const int4 s0 = *(const int4*)(ei + base);
            const int4 s1 = *(const int4*)(ei + base + 4);
            const int4 d0 = *(const int4*)(ei + N_EDGES + base);
            const int4 d1 = *(const int4*)(ei + N_EDGES + base + 4);
            const float4 w0 = *(const float4*)(ew + base);
            const float4 w1 = *(const float4*)(ew + base + 4);
            const int ss[CHUNK] = {s0.x, s0.y, s0.z, s0.w, s1.x, s1.y, s1.z, s1.w};
            const int dd[CHUNK] = {d0.x, d0.y, d0.z, d0.w, d1.x, d1.y, d1.z, d1.w};
            const float ww[CHUNK] = {w0.x, w0.y, w0.z, w0.w, w1.x, w1.y, w1.z, w1.w};
#pragma unroll
            for (int i = 0; i < CHUNK; ++i) {
                r_meta[i] = ss[i] | ((dd[i] & 63) << 17);
                r_w[i]    = __float_as_int(ww[i]);
                r_bin[i]  = dd[i] >> 6;
                atomicAdd(&hist[r_bin[i]], 1);
            }
        }
        __syncthreads();

        for (int b = tid; b < NB; b += PT) {
            const int c = hist[b];
            if (c > 0) hist[b] = atomicAdd(&cnt[b], c);
        }
        __syncthreads();

        if (active) {
#pragma unroll
            for (int i = 0; i < CHUNK; ++i) {
                const int slot = atomicAdd(&hist[r_bin[i]], 1);
                if (slot < CAPB) {
                    recs[(size_t)r_bin[i] * CAPB + slot] = make_int2(r_meta[i], r_w[i]);
                } else {
                    const int q2 = atomicAdd(ovf_cnt, 1);
                    ovf_list[q2] = base + i;
                }
            }
        }
    }
}

// ---------------------------------------------------------------------------
// Kernel 2: per-bin gather, 512 threads.  Records register-staged across
// count/scan barriers (<=3/thread), node-sorted into lcsr, then ONE 8-lane
// group per node with 16 B uint4 sup loads, unrolled x4 for load MLP.
// Overflow edges merged in-register.
// ---------------------------------------------------------------------------
__global__ __launch_bounds__(512) void gather_bins(const unsigned* __restrict__ sup,
                                                   const int* __restrict__ cnt,
                                                   const int2* __restrict__ recs,
                                                   const float* __restrict__ bias,
                                                   const int* __restrict__ ei,
                                                   const float* __restrict__ ew,
                                                   const int* __restrict__ ovf_cnt,
                                                   const int* __restrict__ ovf_list,
                                                   float* __restrict__ out) {
    __shared__ int2 lcsr[CAPB];              // 12,288 B (node-sorted)
    __shared__ int lcnt[NPB];
    __shared__ int lcur[NPB];
    __shared__ int loff[NPB + 1];

    const int tid = threadIdx.x;
    const int bin = blockIdx.x;

    if (tid < NPB) lcnt[tid] = 0;
    __syncthreads();

    int c = cnt[bin];
    c = c < CAPB ? c : CAPB;
    const int2* bk = recs + (size_t)bin * CAPB;
    const int novf = *ovf_cnt;               // hoisted; latency hides below

    // stage into registers (named, no scratch) + per-node counts
    const int i0 = tid, i1 = tid + 512, i2 = tid + 1024;
    int2 ra, rb, rc2;
    int na = -1, nb2 = -1, nc = -1;
    if (i0 < c) ra  = bk[i0];
    if (i1 < c) rb  = bk[i1];
    if (i2 < c) rc2 = bk[i2];
    if (i0 < c) { na  = (ra.x  >> 17) & 63; atomicAdd(&lcnt[na],  1); }
    if (i1 < c) { nb2 = (rb.x  >> 17) & 63; atomicAdd(&lcnt[nb2], 1); }
    if (i2 < c) { nc  = (rc2.x >> 17) & 63; atomicAdd(&lcnt[nc],  1); }
    __syncthreads();

    // wave 0: exclusive scan over 64 node counts
    if (tid < 64) {
        const int my = lcnt[tid];
        int v = my;
#pragma unroll
        for (int d = 1; d < 64; d <<= 1) {
            const int o = __shfl_up(v, d);
            if (tid >= d) v += o;
        }
        loff[tid + 1] = v;
        lcur[tid] = v - my;
        if (tid == 0) loff[0] = 0;
    }
    __syncthreads();

    // place register-held records into node-sorted order
    if (na  >= 0) { const int p = atomicAdd(&lcur[na],  1); lcsr[p] = ra;  }
    if (nb2 >= 0) { const int p = atomicAdd(&lcur[nb2], 1); lcsr[p] = rb;  }
    if (nc  >= 0) { const int p = atomicAdd(&lcur[nc],  1); lcsr[p] = rc2; }
    __syncthreads();

    // one 8-lane group per node; lane l owns channels [l*8, l*8+8)
    const int n = tid >> 3;       // node 0..63
    const int l = tid & 7;
    float4 accA = ((const float4*)bias)[l * 2];
    float4 accB = ((const float4*)bias)[l * 2 + 1];

    const int kend = loff[n + 1];
#pragma unroll 4
    for (int k = loff[n]; k < kend; ++k) {
        const int2 r = lcsr[k];                       // broadcast in group
        const float wc = __int_as_float(r.y);
        const uint4 sv = ((const uint4*)(sup + (size_t)(r.x & 0x1FFFF) * 32))[l];
        accA.x += wc * __uint_as_float(sv.x << 16);
        accA.y += wc * __uint_as_float(sv.x & 0xffff0000u);
        accA.z += wc * __uint_as_float(sv.y << 16);
        accA.w += wc * __uint_as_float(sv.y & 0xffff0000u);
        accB.x += wc * __uint_as_float(sv.z << 16);
        accB.y += wc * __uint_as_float(sv.z & 0xffff0000u);
        accB.z += wc * __uint_as_float(sv.w << 16);
        accB.w += wc * __uint_as_float(sv.w & 0xffff0000u);
    }

    // overflow merge (statistically zero entries; correctness safety net)
    for (int i = 0; i < novf; ++i) {
        const int e = ovf_list[i];
        const int dst = ei[N_EDGES + e];
        if ((dst >> 6) == bin && (dst & 63) == n) {
            const float wv = ew[e];
            const uint4 sv = ((const uint4*)(sup + (size_t)ei[e] * 32))[l];
            accA.x += wv * __uint_as_float(sv.x << 16);
            accA.y += wv * __uint_as_float(sv.x & 0xffff0000u);
            accA.z += wv * __uint_as_float(sv.y << 16);
            accA.w += wv * __uint_as_float(sv.y & 0xffff0000u);
            accB.x += wv * __uint_as_float(sv.z << 16);
            accB.y += wv * __uint_as_float(sv.z & 0xffff0000u);
            accB.z += wv * __uint_as_float(sv.w << 16);
            accB.w += wv * __uint_as_float(sv.w & 0xffff0000u);
        }
    }

    float4* orow = (float4*)(out + (size_t)(bin * NPB + n) * D);
    orow[l * 2]     = accA;
    orow[l * 2 + 1] = accB;
}

// ---------------------------------------------------------------------------
extern "C" void kernel_launch(void* const* d_in, const int* in_sizes, int n_in,
                              void* d_out, int out_size, void* d_ws, size_t ws_size,
                              hipStream_t stream) {
    const float* x      = (const float*)d_in[0];
    const int*   ei     = (const int*)d_in[1];
    const float* ew     = (const float*)d_in[2];
    const float* weight = (const float*)d_in[3];
    const float* bias   = (const float*)d_in[4];
    float* out = (float*)d_out;

    char* ws = (char*)d_ws;
    unsigned* sup   = (unsigned*)(ws + OFF_SUP);
    int*  cnt       = (int*)(ws + OFF_CNT);
    int*  ovf_cnt   = (int*)(ws + OFF_OVC);
    int2* recs      = (int2*)(ws + OFF_REC);
    int*  ovf_list  = (int*)(ws + OFF_OVF);

    // 0. zero bin/overflow counters (1 tiny block)
    zero_cnt<<<1, 1024, 0, stream>>>(cnt);

    // 1. fused: support = X @ W (MFMA)  ||  vectorized edge partition
    gemm_partition<<<GEMM_BLOCKS + NBLK, 1024, 0, stream>>>(
        x, weight, sup, ei, ew, cnt, recs, ovf_cnt, ovf_list);

    // 2. per-bin gather + bias + overflow merge + out write
    gather_bins<<<NB, 512, 0, stream>>>(sup, cnt, recs, bias,
                                        ei, ew, ovf_cnt, ovf_list, out);
}